// Round 5
// baseline (86.267 us; speedup 1.0000x reference)
//
#include <hip/hip_runtime.h>

// VQC 12-qubit statevector, batch=1024. 512 threads/block (8 waves), one batch
// element per block, NR=8 v2f regs/thread. Single layout:
//   Layout C: b11b10b9 = wv (q0,q1,q2), b8..b3 = lane (q3..q8), b2..b0 = reg (q9..q11)
//
// R4 post-mortem: R0 (2 waves/SIMD) == R4 (4 waves/SIMD) == ~38us at ~36% VALU
// duty -> latency-bound at fixed ILPxTLP; grid (1024 blocks) caps 256-thr blocks
// at 16 waves/CU. This version: 8 waves/block -> 32 waves/CU cap (4 blocks/CU x
// 8 waves, LDS 32KB). Cost: 3 wave bits -> exchange fuses Y_q0,q1,q2 as an
// 8-way gather (4x b128 per output amp). Slot math: store amp X at
// (T,m) = (GrayInv(X)[8:0], (z9,z10,z11)); reader at output y reads T=y[8:0],
// all 8 z-variants contiguous in one 64B run. XOR swizzle (^T[5:4] into
// bits[5:4], ^T[6] into bit[6]) puts gather reads at the 8-bank-quad floor.
// Y q9..q11 = reg gates; Y q3..q8 = lane gates (shfl32/16, ds_swizzle 8/4,
// DPP 2/1); layer-0 Y_q0,q1,q2 folded into closed-form encoding; layer-2 Zs
// dropped (diagonal before |amp|^2); layer 2 has no CNOT -> no exchange.

#define PI_F 3.14159265358979323846f
#define NR 8

typedef __attribute__((ext_vector_type(2))) float v2f;
typedef __attribute__((ext_vector_type(4))) float v4f;

__device__ __forceinline__ v2f mkv(float x, float y) { v2f r; r.x = x; r.y = y; return r; }

__device__ __forceinline__ v2f cmul(v2f a, v2f b) {   // complex a*b
    return a.x * b + a.y * mkv(-b.y, b.x);
}
__device__ __forceinline__ v2f cmulc(v2f a, v2f b) {  // a * conj(b)
    return a.x * mkv(b.x, -b.y) + a.y * mkv(b.y, b.x);
}

// ---- cross-lane xor primitives ----
template<int M>
__device__ __forceinline__ float lane_xor_f(float v) {
    if constexpr (M == 1) {        // quad_perm [1,0,3,2]
        return __int_as_float(__builtin_amdgcn_update_dpp(
            0, __float_as_int(v), 0xB1, 0xF, 0xF, false));
    } else if constexpr (M == 2) { // quad_perm [2,3,0,1]
        return __int_as_float(__builtin_amdgcn_update_dpp(
            0, __float_as_int(v), 0x4E, 0xF, 0xF, false));
    } else if constexpr (M == 4) {
        return __int_as_float(__builtin_amdgcn_ds_swizzle(__float_as_int(v), 0x101F));
    } else if constexpr (M == 8) {
        return __int_as_float(__builtin_amdgcn_ds_swizzle(__float_as_int(v), 0x201F));
    } else if constexpr (M == 16) {
        return __shfl_xor(v, 16, 64);
    } else {                       // M == 32
        return __shfl_xor(v, 32, 64);
    }
}
template<int M>
__device__ __forceinline__ v2f lane_xor_v(v2f v) {
    return mkv(lane_xor_f<M>(v.x), lane_xor_f<M>(v.y));
}

template<int RB>
__device__ __forceinline__ void ypow_reg(v2f (&a)[NR], float c, float s) {
    #pragma unroll
    for (int r0 = 0; r0 < NR; ++r0) {
        if ((r0 >> RB) & 1) continue;
        const int r1 = r0 | (1 << RB);
        v2f a0 = a[r0], a1 = a[r1];
        a[r0] = c * a0 - s * a1;
        a[r1] = s * a0 + c * a1;
    }
}

// Y on a LANE bit (xor mask M): a' = c*a + (bit? +s : -s)*partner.
template<int M>
__device__ __forceinline__ void ypow_lane(v2f (&a)[NR], int lane, float c, float s) {
    const float k1 = (lane & M) ? s : -s;
    #pragma unroll
    for (int r = 0; r < NR; ++r) {
        v2f p = lane_xor_v<M>(a[r]);
        a[r] = c * a[r] + k1 * p;
    }
}

__device__ __forceinline__ void ypow_regs(v2f (&a)[NR], const float* __restrict__ th) {
    // reg bit j <-> q(11-j): bit2=q9, bit1=q10, bit0=q11
    { float s,c; __sincosf(0.5f*PI_F*th[18], &s,&c); ypow_reg<2>(a,c,s); }   // q9
    { float s,c; __sincosf(0.5f*PI_F*th[20], &s,&c); ypow_reg<1>(a,c,s); }   // q10
    { float s,c; __sincosf(0.5f*PI_F*th[22], &s,&c); ypow_reg<0>(a,c,s); }   // q11
}

__device__ __forceinline__ void ypow_lanes(v2f (&a)[NR], int lane,
                                           const float* __restrict__ th) {
    // lane bit k <-> q(8-k): q3->xor32, q4->16, q5->8, q6->4, q7->2, q8->1
    { float s,c; __sincosf(0.5f*PI_F*th[6],  &s,&c); ypow_lane<32>(a,lane,c,s); }
    { float s,c; __sincosf(0.5f*PI_F*th[8],  &s,&c); ypow_lane<16>(a,lane,c,s); }
    { float s,c; __sincosf(0.5f*PI_F*th[10], &s,&c); ypow_lane<8>(a,lane,c,s); }
    { float s,c; __sincosf(0.5f*PI_F*th[12], &s,&c); ypow_lane<4>(a,lane,c,s); }
    { float s,c; __sincosf(0.5f*PI_F*th[14], &s,&c); ypow_lane<2>(a,lane,c,s); }
    { float s,c; __sincosf(0.5f*PI_F*th[16], &s,&c); ypow_lane<1>(a,lane,c,s); }
}

// Exchange: CNOT-chain permutation (new[y] = Sum_z K_z old[Z^(Z>>1)],
// Z = (z11,z10,z9, y[8:0])) fused with NEXT layer's Y_q0 (b11), Y_q1 (b10),
// Y_q2 (b9) as an 8-way cross-wave gather.
// Writer of amp X: z11=X11, z10=X10^X11, z9=X9^X10^X11; T = GrayInv(X)[8:0]
// (T_i = parity X_{i..11} = y_i). slot byte = T<<6 | m<<3, m = z9<<2|z10<<1|z11.
// Swizzle: byte ^= (T[5:4])<<4 ^ (T[6])<<6 (slot-bijective; read b128-safe).
__device__ __forceinline__ void exchange_C(v2f (&a)[NR], char* bufc,
                                           int wv, int lane, bool preSync,
                                           float c0, float s0, float c1, float s1,
                                           float c2, float s2) {
    if (preSync) __syncthreads();    // previous exchange's reads done everywhere
    // ---- write side ----
    const int z11 = (wv >> 2) & 1;
    const int z10 = ((wv >> 1) ^ (wv >> 2)) & 1;
    const int z9  = (wv ^ (wv >> 1) ^ (wv >> 2)) & 1;
    const int m_w = (z9 << 2) | (z10 << 1) | z11;
    int U6 = lane; U6 ^= U6 >> 1; U6 ^= U6 >> 2; U6 ^= U6 >> 4; U6 &= 63;
    if (z9) U6 ^= 63;                // U6 = y[8:3] = T[8:3]
    const int kxW   = (U6 >> 1) & 3; // T[5:4]
    const int key6W = (U6 >> 3) & 1; // T[6]
    const int wbase = (U6 << 9) | ((((m_w >> 1) & 3) ^ kxW) << 4) | ((m_w & 1) << 3);
    const int ymask = (U6 & 1) ? 7 : 0;   // y3 broadcast into T[2:0]
    #pragma unroll
    for (int r = 0; r < NR; ++r) {   // amp X = wv<<9 | lane<<3 | r
        const int low3 = ((r ^ (r >> 1) ^ (r >> 2)) & 7) ^ ymask;   // T[2:0]
        *(v2f*)(bufc + (wbase | ((low3 ^ key6W) << 6))) = a[r];
    }
    __syncthreads();
    // ---- read side: output y = wv<<9 | lane<<3 | r, T = lane<<3 | r ----
    const float A0 = (wv & 4) ? s0 : c0, A1 = (wv & 4) ? c0 : -s0;  // Y0[y11,z11]
    const float B0 = (wv & 2) ? s1 : c1, B1 = (wv & 2) ? c1 : -s1;  // Y1[y10,z10]
    const float C0 = (wv & 1) ? s2 : c2, C1 = (wv & 1) ? c2 : -s2;  // Y2[y9,z9]
    float k0[4], k1[4];
    #pragma unroll
    for (int c = 0; c < 4; ++c) {    // chunk c: z9 = c>>1, z10 = c&1; z11 = 0/1
        const float CB = ((c & 2) ? C1 : C0) * ((c & 1) ? B1 : B0);
        k0[c] = CB * A0; k1[c] = CB * A1;
    }
    const int kxR   = (lane >> 1) & 3;   // T[5:4]
    const int key6R = (lane >> 3) & 1;   // T[6]
    const int rbase = lane << 9;
    #pragma unroll
    for (int r = 0; r < NR; ++r) {
        const int hi = rbase | ((r ^ key6R) << 6);
        v4f ch0 = *(const v4f*)(bufc + (hi | ((0 ^ kxR) << 4)));
        v4f ch1 = *(const v4f*)(bufc + (hi | ((1 ^ kxR) << 4)));
        v4f ch2 = *(const v4f*)(bufc + (hi | ((2 ^ kxR) << 4)));
        v4f ch3 = *(const v4f*)(bufc + (hi | ((3 ^ kxR) << 4)));
        a[r] = k0[0]*ch0.xy + k1[0]*ch0.zw
             + k0[1]*ch1.xy + k1[1]*ch1.zw
             + k0[2]*ch2.xy + k1[2]*ch2.zw
             + k0[3]*ch3.xy + k1[3]*ch3.zw;
        asm volatile("" ::: "memory");   // cap in-flight loads at 4 x b128
    }
}

// Fused Z for all 12 qubits (layout C), Gray-code running complex product.
__device__ __forceinline__ void fused_z(v2f (&a)[NR], int wv, int lane,
                                        const float* __restrict__ th) {
    float alpha = ((wv & 4) ? th[1] : 0.0f) + ((wv & 2) ? th[3] : 0.0f)
                + ((wv & 1) ? th[5] : 0.0f);
    #pragma unroll
    for (int k = 0; k < 6; ++k)               // lane bit k <-> q(8-k)
        alpha += ((lane >> k) & 1) ? th[2*(8-k)+1] : 0.0f;
    float zbs, zbc; __sincosf(PI_F * alpha, &zbs, &zbc);
    v2f zq[3];
    #pragma unroll
    for (int j = 0; j < 3; ++j) {             // reg bit j <-> q(11-j)
        float ss, cc; __sincosf(PI_F * th[2*(11-j)+1], &ss, &cc);
        zq[j] = mkv(cc, ss);
    }
    v2f cur = mkv(zbc, zbs);
    a[0] = cmul(a[0], cur);
    #pragma unroll
    for (int k = 1; k < NR; ++k) {
        const int bit = __builtin_ctz(k);
        const int g = k ^ (k >> 1);
        cur = ((g >> bit) & 1) ? cmul(cur, zq[bit]) : cmulc(cur, zq[bit]);
        a[g] = cmul(a[g], cur);
    }
}

__global__ __launch_bounds__(512) void vqc_kernel(
    const float* __restrict__ inputs,   // [1024,12]
    const float* __restrict__ thetas,   // [72] = [3][12][2]
    float* __restrict__ out)            // [1024,12]
{
    __shared__ __align__(16) char bufc[32768];   // exchange buffer; reused as redBuf

    const int b = blockIdx.x;
    const int tid = threadIdx.x;
    const int wv = tid >> 6;         // wv2=b11(q0), wv1=b10(q1), wv0=b9(q2)
    const int lane = tid & 63;
    const float* x = inputs + b * 12;

    v2f a[NR];

    // ---- Encoding (closed form, layout C) with layer-0 Y_q0,q1,q2 folded in.
    // amp = 2^-6 * F0(b11) * F1(b10) * F2(b9) * cis(pi * sum_{q>=3 set} x_q)
    float phb = 0.0f;
    #pragma unroll
    for (int k = 0; k < 6; ++k)               // lane bit k <-> q(8-k)
        phb += ((lane >> k) & 1) ? x[8 - k] : 0.0f;
    float cbs, cbc; __sincosf(PI_F * phb, &cbs, &cbc);
    v2f cisb = mkv(cbc, cbs);
    float e0s, e0c; __sincosf(PI_F * x[0], &e0s, &e0c);
    float e1s, e1c; __sincosf(PI_F * x[1], &e1s, &e1c);
    float e2s, e2c; __sincosf(PI_F * x[2], &e2s, &e2c);
    float sa, ca; __sincosf(0.5f * PI_F * thetas[0], &sa, &ca);
    float sb, cb; __sincosf(0.5f * PI_F * thetas[2], &sb, &cb);
    float sc, cc2; __sincosf(0.5f * PI_F * thetas[4], &sc, &cc2);
    v2f F0 = (wv & 4) ? mkv(sa + ca*e0c,  ca*e0s) : mkv(ca - sa*e0c, -sa*e0s);
    v2f F1 = (wv & 2) ? mkv(sb + cb*e1c,  cb*e1s) : mkv(cb - sb*e1c, -sb*e1s);
    v2f F2 = (wv & 1) ? mkv(sc + cc2*e2c, cc2*e2s) : mkv(cc2 - sc*e2c, -sc*e2s);
    v2f g0 = cmul(cmul(cmul(F0, F1), F2), cisb);
    g0 = g0 * 0.015625f;
    v2f zr[3];
    #pragma unroll
    for (int j = 0; j < 3; ++j) {             // reg bit j <-> q(11-j)
        float ss, zc; __sincosf(PI_F * x[11 - j], &ss, &zc);
        zr[j] = mkv(zc, ss);
    }
    {
        v2f cur = g0;
        a[0] = cur;
        #pragma unroll
        for (int k = 1; k < NR; ++k) {
            const int bit = __builtin_ctz(k);
            const int g = k ^ (k >> 1);
            cur = ((g >> bit) & 1) ? cmul(cur, zr[bit]) : cmulc(cur, zr[bit]);
            a[g] = cur;
        }
    }

    const float* th0 = thetas;
    const float* th1 = thetas + 24;
    const float* th2 = thetas + 48;

    // ----- layer 0 -----
    ypow_regs(a, th0);
    ypow_lanes(a, lane, th0);
    fused_z(a, wv, lane, th0);
    { float s0,c0,s1,c1,s2,c2;
      __sincosf(0.5f*PI_F*th1[0], &s0,&c0);
      __sincosf(0.5f*PI_F*th1[2], &s1,&c1);
      __sincosf(0.5f*PI_F*th1[4], &s2,&c2);
      exchange_C(a, bufc, wv, lane, false, c0,s0,c1,s1,c2,s2); }

    // ----- layer 1 -----
    ypow_regs(a, th1);
    ypow_lanes(a, lane, th1);
    fused_z(a, wv, lane, th1);
    { float s0,c0,s1,c1,s2,c2;
      __sincosf(0.5f*PI_F*th2[0], &s0,&c0);
      __sincosf(0.5f*PI_F*th2[2], &s1,&c1);
      __sincosf(0.5f*PI_F*th2[4], &s2,&c2);
      exchange_C(a, bufc, wv, lane, true, c0,s0,c1,s1,c2,s2); }

    // ----- layer 2 (no CNOT -> no exchange; Zs dropped) -----
    ypow_regs(a, th2);
    ypow_lanes(a, lane, th2);

    // ---- Readout: q0..q2 = wv bits, q3..q8 = lane bits 5..0, q9..q11 = reg
    float totalP = 0.0f;
    float D[3] = {0, 0, 0};
    #pragma unroll
    for (int r = 0; r < NR; ++r) {
        const float p = a[r].x * a[r].x + a[r].y * a[r].y;
        totalP += p;
        #pragma unroll
        for (int j = 0; j < 3; ++j)
            D[j] += ((r >> j) & 1) ? -p : p;
    }
    float* redBuf = (float*)bufc;             // bufc free after last exchange
    __syncthreads();                          // all exchange reads complete
    #pragma unroll
    for (int q = 0; q < 12; ++q) {
        float v;
        if (q == 0)      v = (wv & 4) ? -totalP : totalP;
        else if (q == 1) v = (wv & 2) ? -totalP : totalP;
        else if (q == 2) v = (wv & 1) ? -totalP : totalP;
        else if (q <= 8) v = ((lane >> (8 - q)) & 1) ? -totalP : totalP;
        else             v = D[11 - q];
        v += lane_xor_f<32>(v);
        v += lane_xor_f<16>(v);
        v += lane_xor_f<8>(v);
        v += lane_xor_f<4>(v);
        v += lane_xor_f<2>(v);
        v += lane_xor_f<1>(v);
        if (lane == 0) redBuf[wv * 12 + q] = v;
    }
    __syncthreads();
    if (tid < 12) {
        float s = 0.0f;
        #pragma unroll
        for (int w8 = 0; w8 < 8; ++w8) s += redBuf[w8 * 12 + tid];
        out[b * 12 + tid] = s;
    }
}

extern "C" void kernel_launch(void* const* d_in, const int* in_sizes, int n_in,
                              void* d_out, int out_size, void* d_ws, size_t ws_size,
                              hipStream_t stream) {
    const float* inputs = (const float*)d_in[0];   // [1024,12] f32
    const float* thetas = (const float*)d_in[1];   // [72] f32
    float* out = (float*)d_out;                    // [1024,12] f32
    vqc_kernel<<<dim3(1024), dim3(512), 0, stream>>>(inputs, thetas, out);
}

// Round 6
// 74.644 us; speedup vs baseline: 1.1557x; 1.1557x over previous
//
#include <hip/hip_runtime.h>

// VQC 12-qubit statevector, batch=1024, 128 threads/block (2 waves), NR=32.
// R0's verified structure (all Y gates as reg-pair gates via LDS relabeling
// transposes) + instruction-stream cuts:
//   (1) LDS theta-table: 46 thread-invariant sincos pairs computed once per
//       block (tid<46), broadcast-read -> per-thread sincos 27 -> 10, and no
//       serial sincos between gate stages.
//   (2) packed f32 (ext_vector(2) -> v_pk_fma_f32) for all gate/chain math.
//   (3) exchange_AB write->read sync = s_waitcnt lgkmcnt(0) (wave-local
//       region; lanes lockstep) -> 8 block barriers instead of 11.
//   (4) readout reduce via DPP quad_perm / ds_swizzle imm.
//
// Flat index i (12 bits), qubit q <-> bit (11-q).
// Layout A: b11=w(q0), b10..b6=reg r(q1..q5), b5..b0=lane(q6..q11)
// Layout B: b11=w(q0), b10..b5=lane(q1..q6),  b5? -> b4..b0=reg(q7..q11)
// Per layer: Y q1..5 in-reg [A]; A->B exchange (fuses Y_q6); Y q7..11 in-reg
// [B]; fused Z (all 12, Gray-code product); B->A exchange (fuses CNOT-chain
// permutation x = y^(y>>1) AND next layer's Y_q0). Layer-0 Y_q0 folded into
// closed-form encoding; layer-2 Zs dropped (diagonal before |amp|^2).

#define PI_F 3.14159265358979323846f
#define NR 32
#define PAD 66   // even: keeps b128 pairs 16B-aligned; bank-floor verified (R0)

typedef __attribute__((ext_vector_type(2))) float v2f;

__device__ __forceinline__ v2f mkv(float x, float y) { v2f r; r.x = x; r.y = y; return r; }
__device__ __forceinline__ v2f cmul(v2f a, v2f b) {   // complex a*b
    return a.x * b + a.y * mkv(-b.y, b.x);
}
__device__ __forceinline__ v2f cmulc(v2f a, v2f b) {  // a * conj(b)
    return a.x * mkv(b.x, -b.y) + a.y * mkv(b.y, b.x);
}

// ---- cross-lane xor primitives (readout only) ----
template<int M>
__device__ __forceinline__ float lane_xor_f(float v) {
    if constexpr (M == 1) {        // quad_perm [1,0,3,2]
        return __int_as_float(__builtin_amdgcn_update_dpp(
            0, __float_as_int(v), 0xB1, 0xF, 0xF, false));
    } else if constexpr (M == 2) { // quad_perm [2,3,0,1]
        return __int_as_float(__builtin_amdgcn_update_dpp(
            0, __float_as_int(v), 0x4E, 0xF, 0xF, false));
    } else if constexpr (M == 4) {
        return __int_as_float(__builtin_amdgcn_ds_swizzle(__float_as_int(v), 0x101F));
    } else if constexpr (M == 8) {
        return __int_as_float(__builtin_amdgcn_ds_swizzle(__float_as_int(v), 0x201F));
    } else if constexpr (M == 16) {
        return __int_as_float(__builtin_amdgcn_ds_swizzle(__float_as_int(v), 0x401F));
    } else {                       // M == 32: cross-half
        return __shfl_xor(v, 32, 64);
    }
}

template<int RB>
__device__ __forceinline__ void ypow_reg(v2f (&a)[NR], float c, float s) {
    #pragma unroll
    for (int r0 = 0; r0 < NR; ++r0) {
        if ((r0 >> RB) & 1) continue;
        const int r1 = r0 | (1 << RB);
        v2f a0 = a[r0], a1 = a[r1];
        a[r0] = c * a0 - s * a1;
        a[r1] = s * a0 + c * a1;
    }
}

// yt = &thTab[l*12]; layout A: q1..q5 -> reg bits 4..0
__device__ __forceinline__ void ypowA(v2f (&a)[NR], const v2f* __restrict__ yt) {
    { v2f t = yt[1]; ypow_reg<4>(a, t.x, t.y); }
    { v2f t = yt[2]; ypow_reg<3>(a, t.x, t.y); }
    { v2f t = yt[3]; ypow_reg<2>(a, t.x, t.y); }
    { v2f t = yt[4]; ypow_reg<1>(a, t.x, t.y); }
    { v2f t = yt[5]; ypow_reg<0>(a, t.x, t.y); }
}
// layout B: q7..q11 -> reg bits 4..0
__device__ __forceinline__ void ypowB(v2f (&a)[NR], const v2f* __restrict__ yt) {
    { v2f t = yt[7];  ypow_reg<4>(a, t.x, t.y); }
    { v2f t = yt[8];  ypow_reg<3>(a, t.x, t.y); }
    { v2f t = yt[9];  ypow_reg<2>(a, t.x, t.y); }
    { v2f t = yt[10]; ypow_reg<1>(a, t.x, t.y); }
    { v2f t = yt[11]; ypow_reg<0>(a, t.x, t.y); }
}

// A->B transpose, fusing Y on q6 (b5). Wave-local (b11 untouched): writes and
// reads stay inside this wave's region -> lgkmcnt(0) is the only sync needed.
template<bool PRE_SYNC>
__device__ __forceinline__ void exchange_AB(v2f (&a)[NR], v2f* buf,
                                            int w, int lane, float c6, float s6) {
    v2f* wb = buf + w * (NR * PAD);
    if (PRE_SYNC) __syncthreads();         // prev BA's cross-wave reads done
    #pragma unroll
    for (int r = 0; r < NR; ++r)           // slot = [b10..b6 | b4..b0 | b5]
        wb[r * PAD + (lane & 31) * 2 + (lane >> 5)] = a[r];
    asm volatile("s_waitcnt lgkmcnt(0)" ::: "memory");   // wave-local drain
    const int g = lane >> 1;               // b10..b6 of output
    const float k0 = (lane & 1) ? s6 : c6;
    const float k1 = (lane & 1) ? c6 : -s6;
    #pragma unroll
    for (int r = 0; r < NR; ++r) {
        v2f p0 = wb[g * PAD + r * 2];      // b5 = 0
        v2f p1 = wb[g * PAD + r * 2 + 1];  // b5 = 1
        a[r] = k0 * p0 + k1 * p1;
    }
}

// B->A transpose, fusing the CNOT-chain permutation (new[y] = old[y ^ (y>>1)])
// and the NEXT layer's Y_q0 (mixes b11; pairs stored adjacent).
__device__ __forceinline__ void exchange_BA(v2f (&a)[NR], v2f* buf,
                                            int w, int lane, float c0, float s0) {
    __syncthreads();                       // all waves' AB-region reads done
    const int p6w = lane ^ (w << 5);       // (x10^x11)<<5 | x9..x5 for this writer
    #pragma unroll
    for (int r = 0; r < NR; ++r)           // slot = p6*PAD + (x4..x0)*2 + x11
        buf[p6w * PAD + r * 2 + w] = a[r];
    __syncthreads();
    const float k0 = w ? s0 : c0;
    const float k1 = w ? c0 : -s0;
    #pragma unroll
    for (int rp = 0; rp < NR; ++rp) {
        const int ylow = (rp << 6) | lane;         // b10..b0 of output index
        const int t = ylow ^ (ylow >> 1);          // Gray inverse (11 bits)
        const int base = (t >> 5) * PAD + (t & 31) * 2;
        v2f p0 = buf[base];                        // input b11 = 0
        v2f p1 = buf[base + 1];                    // input b11 = 1
        a[rp] = k0 * p0 + k1 * p1;
    }
}

// Fused Z for all 12 qubits, layout B. Gray-code running complex product;
// reg-bit phases zt[0..4] come from the LDS table, lane/wave part is the one
// per-thread sincos.
__device__ __forceinline__ void fused_z_B(v2f (&a)[NR], int w, int lane,
                                          const float* __restrict__ th,
                                          const v2f* __restrict__ zt) {
    float alpha = w ? th[1] : 0.0f;
    #pragma unroll
    for (int k = 0; k < 6; ++k)                 // lane bit k <-> q(6-k)
        alpha += ((lane >> k) & 1) ? th[2*(6-k)+1] : 0.0f;
    float zs, zc; __sincosf(PI_F * alpha, &zs, &zc);
    v2f zq[5];
    #pragma unroll
    for (int j = 0; j < 5; ++j) zq[j] = zt[j];  // reg bit j <-> q(11-j)
    v2f cur = mkv(zc, zs);
    a[0] = cmul(a[0], cur);
    #pragma unroll
    for (int k = 1; k < NR; ++k) {
        const int bit = __builtin_ctz(k);
        const int g = k ^ (k >> 1);
        cur = ((g >> bit) & 1) ? cmul(cur, zq[bit]) : cmulc(cur, zq[bit]);
        a[g] = cmul(a[g], cur);
    }
}

__global__ __launch_bounds__(128) void vqc_kernel(
    const float* __restrict__ inputs,   // [1024,12]
    const float* __restrict__ thetas,   // [72] = [3][12][2]
    float* __restrict__ out)            // [1024,12]
{
    __shared__ __align__(16) v2f buf[64 * PAD];   // 33,792 B exchange buffer
    __shared__ v2f thTab[46];                     // 36 Y pairs + 10 Z pairs
    __shared__ float redBuf[24];

    const int b = blockIdx.x;
    const int tid = threadIdx.x;
    const int w = tid >> 6;
    const int lane = tid & 63;
    const float* x = inputs + b * 12;

    // ---- theta table: thread-invariant sincos computed once per block.
    // Y[l][q] = (cos,sin)(0.5*pi*th[l*24+2q]) at thTab[l*12+q]  (l=0..2,q=0..11)
    // Z[l][j] = cis(pi*th[l*24+2*(11-j)+1])  at thTab[36+l*5+j] (l=0..1,j=0..4)
    if (tid < 36) {
        const int l = tid / 12, q = tid % 12;
        float s, c; __sincosf(0.5f * PI_F * thetas[l * 24 + 2 * q], &s, &c);
        thTab[tid] = mkv(c, s);
    } else if (tid < 46) {
        const int j = tid - 36, l = j / 5, jj = j % 5;
        float s, c; __sincosf(PI_F * thetas[l * 24 + 2 * (11 - jj) + 1], &s, &c);
        thTab[tid] = mkv(c, s);
    }

    // ---- x-dependent encoding pieces (overlap with table fill, pre-barrier)
    float phb = 0.0f;
    #pragma unroll
    for (int k = 0; k < 6; ++k)                 // layout-A lane bit k <-> q(11-k)
        phb += ((lane >> k) & 1) ? x[11 - k] : 0.0f;
    float cbs, cbc; __sincosf(PI_F * phb, &cbs, &cbc);
    v2f cisb = mkv(cbc, cbs);
    float es, ec; __sincosf(PI_F * x[0], &es, &ec);
    v2f zr[5];
    #pragma unroll
    for (int j = 0; j < 5; ++j) {               // layout-A reg bit j <-> q(5-j)
        float ss, cc; __sincosf(PI_F * x[5 - j], &ss, &cc);
        zr[j] = mkv(cc, ss);
    }

    __syncthreads();                            // table ready

    // ---- Encoding (closed form) with layer-0 Y_q0 folded in.
    // amp = 2^-6 * Fw * cis(pi*phi_rest), Fw = {c0 - s0*E, s0 + c0*E}, E=cis(pi*x0)
    v2f a[NR];
    {
        v2f t0 = thTab[0];                      // (c0, s0) of 0.5*pi*theta0
        v2f Fw = w ? mkv(t0.y + t0.x * ec,  t0.x * es)
                   : mkv(t0.x - t0.y * ec, -t0.y * es);
        v2f cur = cmul(Fw, cisb) * 0.015625f;
        a[0] = cur;
        #pragma unroll
        for (int k = 1; k < NR; ++k) {
            const int bit = __builtin_ctz(k);
            const int g = k ^ (k >> 1);
            cur = ((g >> bit) & 1) ? cmul(cur, zr[bit]) : cmulc(cur, zr[bit]);
            a[g] = cur;
        }
    }

    // ----- layer 0 -----
    ypowA(a, &thTab[0]);
    { v2f t = thTab[6];  exchange_AB<false>(a, buf, w, lane, t.x, t.y); }
    ypowB(a, &thTab[0]);
    fused_z_B(a, w, lane, thetas, &thTab[36]);
    { v2f t = thTab[12]; exchange_BA(a, buf, w, lane, t.x, t.y); }   // next-layer Y_q0

    // ----- layer 1 -----
    ypowA(a, &thTab[12]);
    { v2f t = thTab[18]; exchange_AB<true>(a, buf, w, lane, t.x, t.y); }
    ypowB(a, &thTab[12]);
    fused_z_B(a, w, lane, thetas + 24, &thTab[41]);
    { v2f t = thTab[24]; exchange_BA(a, buf, w, lane, t.x, t.y); }   // next-layer Y_q0

    // ----- layer 2 (no CNOT; Zs dropped — diagonal before |amp|^2) -----
    ypowA(a, &thTab[24]);
    { v2f t = thTab[30]; exchange_AB<true>(a, buf, w, lane, t.x, t.y); }
    ypowB(a, &thTab[24]);

    // ---- Readout in layout B: b11=w(q0), lane bit k<->q(6-k), reg bit j<->q(11-j)
    float totalP = 0.0f;
    float D[5] = {0, 0, 0, 0, 0};
    #pragma unroll
    for (int r = 0; r < NR; ++r) {
        const float p = a[r].x * a[r].x + a[r].y * a[r].y;
        totalP += p;
        #pragma unroll
        for (int j = 0; j < 5; ++j)
            D[j] += ((r >> j) & 1) ? -p : p;
    }
    #pragma unroll
    for (int q = 0; q < 12; ++q) {
        float v;
        if (q == 0)       v = w ? -totalP : totalP;
        else if (q <= 6)  v = ((lane >> (6 - q)) & 1) ? -totalP : totalP;
        else              v = D[11 - q];
        v += lane_xor_f<32>(v);
        v += lane_xor_f<16>(v);
        v += lane_xor_f<8>(v);
        v += lane_xor_f<4>(v);
        v += lane_xor_f<2>(v);
        v += lane_xor_f<1>(v);
        if (lane == 0) redBuf[w * 12 + q] = v;
    }
    __syncthreads();
    if (tid < 12) out[b * 12 + tid] = redBuf[tid] + redBuf[12 + tid];
}

extern "C" void kernel_launch(void* const* d_in, const int* in_sizes, int n_in,
                              void* d_out, int out_size, void* d_ws, size_t ws_size,
                              hipStream_t stream) {
    const float* inputs = (const float*)d_in[0];   // [1024,12] f32
    const float* thetas = (const float*)d_in[1];   // [72] f32
    float* out = (float*)d_out;                    // [1024,12] f32
    vqc_kernel<<<dim3(1024), dim3(128), 0, stream>>>(inputs, thetas, out);
}

// Round 7
// 74.606 us; speedup vs baseline: 1.1563x; 1.0005x over previous
//
#include <hip/hip_runtime.h>

// VQC 12-qubit statevector, batch=1024, 128 threads/block (2 waves), NR=32.
// R6 structure (LDS theta-table, pk math, reg-pair Y gates via A/B relabel
// transposes, lgkm-drain AB exchanges) + R7 latency cuts:
//   (1) 4-way parallel Gray-code chains (encoding + 2x fused_z): dependent
//       cmul depth 31 -> ~10 (chain starts at k=8,16,24 cost 1 cmul each).
//   (2) explicit ds_read_b128 in both exchanges (v4f loads; PAD=66 keeps
//       16B alignment: row stride 528B, pair offsets 16B).
//   (3) readout: plain totalP tree folded once, reused for q0 (12->11 trees).
//
// Flat index i (12 bits), qubit q <-> bit (11-q).
// Layout A: b11=w(q0), b10..b6=reg r(q1..q5), b5..b0=lane(q6..q11)
// Layout B: b11=w(q0), b10..b5=lane(q1..q6),  b4..b0=reg(q7..q11)
// Per layer: Y q1..5 in-reg [A]; A->B exchange (fuses Y_q6); Y q7..11 in-reg
// [B]; fused Z (all 12, Gray-code product); B->A exchange (fuses CNOT-chain
// permutation x = y^(y>>1) AND next layer's Y_q0). Layer-0 Y_q0 folded into
// closed-form encoding; layer-2 Zs dropped (diagonal before |amp|^2).

#define PI_F 3.14159265358979323846f
#define NR 32
#define PAD 66   // even: 528B rows -> b128 pairs stay 16B-aligned

typedef __attribute__((ext_vector_type(2))) float v2f;
typedef __attribute__((ext_vector_type(4))) float v4f;

__device__ __forceinline__ v2f mkv(float x, float y) { v2f r; r.x = x; r.y = y; return r; }
__device__ __forceinline__ v2f cmul(v2f a, v2f b) {   // complex a*b
    return a.x * b + a.y * mkv(-b.y, b.x);
}
__device__ __forceinline__ v2f cmulc(v2f a, v2f b) {  // a * conj(b)
    return a.x * mkv(b.x, -b.y) + a.y * mkv(b.y, b.x);
}

// ---- cross-lane xor primitives (readout only) ----
template<int M>
__device__ __forceinline__ float lane_xor_f(float v) {
    if constexpr (M == 1) {        // quad_perm [1,0,3,2]
        return __int_as_float(__builtin_amdgcn_update_dpp(
            0, __float_as_int(v), 0xB1, 0xF, 0xF, false));
    } else if constexpr (M == 2) { // quad_perm [2,3,0,1]
        return __int_as_float(__builtin_amdgcn_update_dpp(
            0, __float_as_int(v), 0x4E, 0xF, 0xF, false));
    } else if constexpr (M == 4) {
        return __int_as_float(__builtin_amdgcn_ds_swizzle(__float_as_int(v), 0x101F));
    } else if constexpr (M == 8) {
        return __int_as_float(__builtin_amdgcn_ds_swizzle(__float_as_int(v), 0x201F));
    } else if constexpr (M == 16) {
        return __int_as_float(__builtin_amdgcn_ds_swizzle(__float_as_int(v), 0x401F));
    } else {                       // M == 32: cross-half
        return __shfl_xor(v, 32, 64);
    }
}

template<int RB>
__device__ __forceinline__ void ypow_reg(v2f (&a)[NR], float c, float s) {
    #pragma unroll
    for (int r0 = 0; r0 < NR; ++r0) {
        if ((r0 >> RB) & 1) continue;
        const int r1 = r0 | (1 << RB);
        v2f a0 = a[r0], a1 = a[r1];
        a[r0] = c * a0 - s * a1;
        a[r1] = s * a0 + c * a1;
    }
}

// yt = &thTab[l*12]; layout A: q1..q5 -> reg bits 4..0
__device__ __forceinline__ void ypowA(v2f (&a)[NR], const v2f* __restrict__ yt) {
    { v2f t = yt[1]; ypow_reg<4>(a, t.x, t.y); }
    { v2f t = yt[2]; ypow_reg<3>(a, t.x, t.y); }
    { v2f t = yt[3]; ypow_reg<2>(a, t.x, t.y); }
    { v2f t = yt[4]; ypow_reg<1>(a, t.x, t.y); }
    { v2f t = yt[5]; ypow_reg<0>(a, t.x, t.y); }
}
// layout B: q7..q11 -> reg bits 4..0
__device__ __forceinline__ void ypowB(v2f (&a)[NR], const v2f* __restrict__ yt) {
    { v2f t = yt[7];  ypow_reg<4>(a, t.x, t.y); }
    { v2f t = yt[8];  ypow_reg<3>(a, t.x, t.y); }
    { v2f t = yt[9];  ypow_reg<2>(a, t.x, t.y); }
    { v2f t = yt[10]; ypow_reg<1>(a, t.x, t.y); }
    { v2f t = yt[11]; ypow_reg<0>(a, t.x, t.y); }
}

// A->B transpose, fusing Y on q6 (b5). Wave-local (b11 untouched): writes and
// reads stay inside this wave's region -> lgkmcnt(0) is the only sync needed.
template<bool PRE_SYNC>
__device__ __forceinline__ void exchange_AB(v2f (&a)[NR], v2f* buf,
                                            int w, int lane, float c6, float s6) {
    v2f* wb = buf + w * (NR * PAD);
    if (PRE_SYNC) __syncthreads();         // prev BA's cross-wave reads done
    #pragma unroll
    for (int r = 0; r < NR; ++r)           // slot = [b10..b6 | b4..b0 | b5]
        wb[r * PAD + (lane & 31) * 2 + (lane >> 5)] = a[r];
    asm volatile("s_waitcnt lgkmcnt(0)" ::: "memory");   // wave-local drain
    const int g = lane >> 1;               // b10..b6 of output
    const float k0 = (lane & 1) ? s6 : c6;
    const float k1 = (lane & 1) ? c6 : -s6;
    #pragma unroll
    for (int r = 0; r < NR; ++r) {
        v4f p = *(const v4f*)(&wb[g * PAD + r * 2]);   // (b5=0, b5=1) pair
        a[r] = k0 * p.xy + k1 * p.zw;
    }
}

// B->A transpose, fusing the CNOT-chain permutation (new[y] = old[y ^ (y>>1)])
// and the NEXT layer's Y_q0 (mixes b11; pairs stored adjacent).
__device__ __forceinline__ void exchange_BA(v2f (&a)[NR], v2f* buf,
                                            int w, int lane, float c0, float s0) {
    __syncthreads();                       // all waves' AB-region reads done
    const int p6w = lane ^ (w << 5);       // (x10^x11)<<5 | x9..x5 for this writer
    #pragma unroll
    for (int r = 0; r < NR; ++r)           // slot = p6*PAD + (x4..x0)*2 + x11
        buf[p6w * PAD + r * 2 + w] = a[r];
    __syncthreads();
    const float k0 = w ? s0 : c0;
    const float k1 = w ? c0 : -s0;
    #pragma unroll
    for (int rp = 0; rp < NR; ++rp) {
        const int ylow = (rp << 6) | lane;         // b10..b0 of output index
        const int t = ylow ^ (ylow >> 1);          // Gray inverse (11 bits)
        const int base = (t >> 5) * PAD + (t & 31) * 2;
        v4f p = *(const v4f*)(&buf[base]);         // (b11=0, b11=1) pair
        a[rp] = k0 * p.xy + k1 * p.zw;
    }
}

// Fused Z for all 12 qubits, layout B. Gray-code running complex product,
// split into 4 parallel sub-chains (k = 8m..8m+7) -> dependent depth ~10.
__device__ __forceinline__ void fused_z_B(v2f (&a)[NR], int w, int lane,
                                          const float* __restrict__ th,
                                          const v2f* __restrict__ zt) {
    float alpha = w ? th[1] : 0.0f;
    #pragma unroll
    for (int k = 0; k < 6; ++k)                 // lane bit k <-> q(6-k)
        alpha += ((lane >> k) & 1) ? th[2*(6-k)+1] : 0.0f;
    float zs, zc; __sincosf(PI_F * alpha, &zs, &zc);
    v2f zq[5];
    #pragma unroll
    for (int j = 0; j < 5; ++j) zq[j] = zt[j];  // reg bit j <-> q(11-j)
    const v2f base = mkv(zc, zs);
    v2f curs[4];
    curs[0] = base;
    curs[1] = cmul(base, cmul(zq[2], zq[3]));   // g(8)  = 12 = bits {2,3}
    curs[2] = cmul(base, cmul(zq[3], zq[4]));   // g(16) = 24 = bits {3,4}
    curs[3] = cmul(base, cmul(zq[2], zq[4]));   // g(24) = 20 = bits {2,4}
    a[0]  = cmul(a[0],  curs[0]);
    a[12] = cmul(a[12], curs[1]);
    a[24] = cmul(a[24], curs[2]);
    a[20] = cmul(a[20], curs[3]);
    #pragma unroll
    for (int i = 1; i < 8; ++i) {
        #pragma unroll
        for (int m = 0; m < 4; ++m) {
            const int k = 8 * m + i;
            const int bit = __builtin_ctz(i);
            const int g = k ^ (k >> 1);
            curs[m] = ((g >> bit) & 1) ? cmul(curs[m], zq[bit])
                                       : cmulc(curs[m], zq[bit]);
            a[g] = cmul(a[g], curs[m]);
        }
    }
}

__global__ __launch_bounds__(128) void vqc_kernel(
    const float* __restrict__ inputs,   // [1024,12]
    const float* __restrict__ thetas,   // [72] = [3][12][2]
    float* __restrict__ out)            // [1024,12]
{
    __shared__ __align__(16) v2f buf[64 * PAD];   // 33,792 B exchange buffer
    __shared__ v2f thTab[46];                     // 36 Y pairs + 10 Z pairs
    __shared__ float redBuf[24];

    const int b = blockIdx.x;
    const int tid = threadIdx.x;
    const int w = tid >> 6;
    const int lane = tid & 63;
    const float* x = inputs + b * 12;

    // ---- theta table: thread-invariant sincos computed once per block.
    if (tid < 36) {
        const int l = tid / 12, q = tid % 12;
        float s, c; __sincosf(0.5f * PI_F * thetas[l * 24 + 2 * q], &s, &c);
        thTab[tid] = mkv(c, s);
    } else if (tid < 46) {
        const int j = tid - 36, l = j / 5, jj = j % 5;
        float s, c; __sincosf(PI_F * thetas[l * 24 + 2 * (11 - jj) + 1], &s, &c);
        thTab[tid] = mkv(c, s);
    }

    // ---- x-dependent encoding pieces (overlap with table fill, pre-barrier)
    float phb = 0.0f;
    #pragma unroll
    for (int k = 0; k < 6; ++k)                 // layout-A lane bit k <-> q(11-k)
        phb += ((lane >> k) & 1) ? x[11 - k] : 0.0f;
    float cbs, cbc; __sincosf(PI_F * phb, &cbs, &cbc);
    v2f cisb = mkv(cbc, cbs);
    float es, ec; __sincosf(PI_F * x[0], &es, &ec);
    v2f zr[5];
    #pragma unroll
    for (int j = 0; j < 5; ++j) {               // layout-A reg bit j <-> q(5-j)
        float ss, cc; __sincosf(PI_F * x[5 - j], &ss, &cc);
        zr[j] = mkv(cc, ss);
    }

    __syncthreads();                            // table ready

    // ---- Encoding (closed form) with layer-0 Y_q0 folded in; 4-way chains.
    v2f a[NR];
    {
        v2f t0 = thTab[0];                      // (c0, s0) of 0.5*pi*theta0
        v2f Fw = w ? mkv(t0.y + t0.x * ec,  t0.x * es)
                   : mkv(t0.x - t0.y * ec, -t0.y * es);
        const v2f g0 = cmul(Fw, cisb) * 0.015625f;
        v2f curs[4];
        curs[0] = g0;
        curs[1] = cmul(g0, cmul(zr[2], zr[3]));   // g(8)  = 12
        curs[2] = cmul(g0, cmul(zr[3], zr[4]));   // g(16) = 24
        curs[3] = cmul(g0, cmul(zr[2], zr[4]));   // g(24) = 20
        a[0] = curs[0]; a[12] = curs[1]; a[24] = curs[2]; a[20] = curs[3];
        #pragma unroll
        for (int i = 1; i < 8; ++i) {
            #pragma unroll
            for (int m = 0; m < 4; ++m) {
                const int k = 8 * m + i;
                const int bit = __builtin_ctz(i);
                const int g = k ^ (k >> 1);
                curs[m] = ((g >> bit) & 1) ? cmul(curs[m], zr[bit])
                                           : cmulc(curs[m], zr[bit]);
                a[g] = curs[m];
            }
        }
    }

    // ----- layer 0 -----
    ypowA(a, &thTab[0]);
    { v2f t = thTab[6];  exchange_AB<false>(a, buf, w, lane, t.x, t.y); }
    ypowB(a, &thTab[0]);
    fused_z_B(a, w, lane, thetas, &thTab[36]);
    { v2f t = thTab[12]; exchange_BA(a, buf, w, lane, t.x, t.y); }   // next-layer Y_q0

    // ----- layer 1 -----
    ypowA(a, &thTab[12]);
    { v2f t = thTab[18]; exchange_AB<true>(a, buf, w, lane, t.x, t.y); }
    ypowB(a, &thTab[12]);
    fused_z_B(a, w, lane, thetas + 24, &thTab[41]);
    { v2f t = thTab[24]; exchange_BA(a, buf, w, lane, t.x, t.y); }   // next-layer Y_q0

    // ----- layer 2 (no CNOT; Zs dropped — diagonal before |amp|^2) -----
    ypowA(a, &thTab[24]);
    { v2f t = thTab[30]; exchange_AB<true>(a, buf, w, lane, t.x, t.y); }
    ypowB(a, &thTab[24]);

    // ---- Readout in layout B: b11=w(q0), lane bit k<->q(6-k), reg bit j<->q(11-j)
    float totalP = 0.0f;
    float D[5] = {0, 0, 0, 0, 0};
    #pragma unroll
    for (int r = 0; r < NR; ++r) {
        const float p = a[r].x * a[r].x + a[r].y * a[r].y;
        totalP += p;
        #pragma unroll
        for (int j = 0; j < 5; ++j)
            D[j] += ((r >> j) & 1) ? -p : p;
    }
    // q0: plain fold of totalP, sign by wave bit
    {
        float T = totalP;
        T += lane_xor_f<32>(T);
        T += lane_xor_f<16>(T);
        T += lane_xor_f<8>(T);
        T += lane_xor_f<4>(T);
        T += lane_xor_f<2>(T);
        T += lane_xor_f<1>(T);
        if (lane == 0) redBuf[w * 12 + 0] = w ? -T : T;
    }
    #pragma unroll
    for (int q = 1; q < 12; ++q) {
        float v;
        if (q <= 6)  v = ((lane >> (6 - q)) & 1) ? -totalP : totalP;
        else         v = D[11 - q];
        v += lane_xor_f<32>(v);
        v += lane_xor_f<16>(v);
        v += lane_xor_f<8>(v);
        v += lane_xor_f<4>(v);
        v += lane_xor_f<2>(v);
        v += lane_xor_f<1>(v);
        if (lane == 0) redBuf[w * 12 + q] = v;
    }
    __syncthreads();
    if (tid < 12) out[b * 12 + tid] = redBuf[tid] + redBuf[12 + tid];
}

extern "C" void kernel_launch(void* const* d_in, const int* in_sizes, int n_in,
                              void* d_out, int out_size, void* d_ws, size_t ws_size,
                              hipStream_t stream) {
    const float* inputs = (const float*)d_in[0];   // [1024,12] f32
    const float* thetas = (const float*)d_in[1];   // [72] f32
    float* out = (float*)d_out;                    // [1024,12] f32
    vqc_kernel<<<dim3(1024), dim3(128), 0, stream>>>(inputs, thetas, out);
}